// Round 1
// baseline (804.057 us; speedup 1.0000x reference)
//
#include <hip/hip_runtime.h>
#include <math.h>

#define N_   4
#define C_   128
#define CO_  128
#define H_   96
#define W_   96
#define HW_  (H_*W_)
#define NJ   27            // 18 offset channels + 9 modulation channels
#define BN_EPS_ 1e-5f

// ---------------------------------------------------------------------------
// ws layout (floats):
//   convout : N*27*HW            = 995328
//   wT      : 9*128*128          = 147456   (weight transposed to [k][c][o])
//   out_pre : N*128*HW           = 4718592  (pre-BN activations)
//   bn      : 256                (sum[128], sumsq[128])
// total ~23.5 MB
// ---------------------------------------------------------------------------

// K1: 3x3 conv over x producing the 27 offset/mod channels.
// grid (36, 27, 4), block 256. One thread per (n, j, pixel).
__global__ __launch_bounds__(256)
void k_offconv(const float* __restrict__ x,
               const float* __restrict__ offw, const float* __restrict__ offb,
               const float* __restrict__ modw, const float* __restrict__ modb,
               float* __restrict__ convout) {
    __shared__ float wl[1152];
    const int j = blockIdx.y;
    const int n = blockIdx.z;
    const int t = threadIdx.x;
    const float* wsrc = (j < 18) ? (offw + j*1152) : (modw + (j-18)*1152);
    for (int i = t; i < 1152; i += 256) wl[i] = wsrc[i];
    __syncthreads();
    const int pix = blockIdx.x*256 + t;          // 0..9215 (exact)
    const int h = pix / W_, w = pix % W_;
    float acc = (j < 18) ? offb[j] : modb[j-18];
    const float* xn = x + (size_t)n*C_*HW_;
    for (int c = 0; c < C_; ++c) {
        const float* xp = xn + c*HW_;
        const float* wc = wl + c*9;
        #pragma unroll
        for (int ky = 0; ky < 3; ++ky) {
            const int y = h + ky - 1;
            if (y < 0 || y >= H_) continue;
            const float* row = xp + y*W_;
            #pragma unroll
            for (int kx = 0; kx < 3; ++kx) {
                const int xx = w + kx - 1;
                if (xx < 0 || xx >= W_) continue;
                acc += row[xx] * wc[ky*3+kx];
            }
        }
    }
    convout[(size_t)(n*NJ + j)*HW_ + pix] = acc;
}

// K1b: weight (O,C,3,3) -> wT[k][c][o] for coalesced staging in K2.
__global__ __launch_bounds__(256)
void k_wtrans(const float* __restrict__ weight, float* __restrict__ wT) {
    const int e = blockIdx.x*256 + threadIdx.x;
    if (e >= 9*C_*CO_) return;
    const int o = e & 127, c = (e >> 7) & 127, kk = e >> 14;
    wT[e] = weight[(o*C_ + c)*9 + kk];
}

// K2: bilinear sampling + main contraction + BN partial sums.
// grid = N*H*3 blocks, 256 threads. Tile: 128 o x 32 pixels; thread: 4o x 4p.
__global__ __launch_bounds__(256)
void k_main(const float* __restrict__ x,
            const float* __restrict__ convout,
            const float* __restrict__ wT,
            const float* __restrict__ bias,
            float* __restrict__ out_pre,
            float* __restrict__ bnsum, float* __restrict__ bnsq) {
    __shared__ int   sidx[9][32][4];
    __shared__ float swgt[9][32][4];
    __shared__ float wl[32*128];     // [c'][o]
    __shared__ float sl[32*32];      // [c'][p]

    const int t  = threadIdx.x;
    const int bid = blockIdx.x;                   // n*H*3 + h*3 + wc
    const int wcb = bid % 3;
    const int h   = (bid/3) % H_;
    const int n   = bid / (3*H_);
    const int w0  = wcb*32;

    // ---- Phase A: bilinear metadata for 9 taps x 32 pixels ----
    const float* co = convout + (size_t)n*NJ*HW_;
    for (int it = t; it < 9*32; it += 256) {
        const int k = it >> 5, p = it & 31;
        const int w = w0 + p;
        const int pixoff = h*W_ + w;
        const float offy = co[(2*k  )*HW_ + pixoff];
        const float offx = co[(2*k+1)*HW_ + pixoff];
        const float mraw = co[(18+k )*HW_ + pixoff];
        const float m = 2.0f / (1.0f + expf(-mraw));
        const float sy = offy + (float)h + (float)(k/3 - 1);
        const float sx = offx + (float)w + (float)(k%3 - 1);
        const float y0f = floorf(sy), x0f = floorf(sx);
        const float wy1 = sy - y0f, wy0 = 1.0f - wy1;
        const float wx1 = sx - x0f, wx0 = 1.0f - wx1;
        const float yf[2] = {y0f, y0f + 1.0f};
        const float xf[2] = {x0f, x0f + 1.0f};
        const float wy[2] = {wy0, wy1};
        const float wx[2] = {wx0, wx1};
        #pragma unroll
        for (int cy = 0; cy < 2; ++cy) {
            #pragma unroll
            for (int cx = 0; cx < 2; ++cx) {
                const bool valid = (yf[cy] >= 0.0f) & (yf[cy] <= (float)(H_-1)) &
                                   (xf[cx] >= 0.0f) & (xf[cx] <= (float)(W_-1));
                const int yi = (int)fminf(fmaxf(yf[cy], 0.0f), (float)(H_-1));
                const int xi = (int)fminf(fmaxf(xf[cx], 0.0f), (float)(W_-1));
                sidx[k][p][cy*2+cx] = yi*W_ + xi;
                swgt[k][p][cy*2+cx] = valid ? (wy[cy]*wx[cx]*m) : 0.0f;
            }
        }
    }
    __syncthreads();

    float acc[4][4];
    #pragma unroll
    for (int i = 0; i < 4; ++i)
        #pragma unroll
        for (int j = 0; j < 4; ++j) acc[i][j] = 0.0f;

    const int pg = t & 7;        // p = pg*4 .. +3
    const int og = t >> 3;       // o = og*4 .. +3

    for (int k = 0; k < 9; ++k) {
        for (int cc = 0; cc < 4; ++cc) {
            const int cbase = cc*32;
            // stage weights: wT[(k*128 + cbase+c')*128 + o] -> wl[c'][o]
            #pragma unroll
            for (int i = 0; i < 16; ++i) {
                const int e  = i*256 + t;
                const int o  = e & 127;
                const int cp = e >> 7;
                wl[cp*128 + o] = wT[((size_t)k*C_ + cbase + cp)*CO_ + o];
            }
            // stage sampled values: sl[c'][p]
            {
                const int p  = t & 31;
                const int c0 = t >> 5;
                const int*   ip = sidx[k][p];
                const float* wp = swgt[k][p];
                const float w0c = wp[0], w1c = wp[1], w2c = wp[2], w3c = wp[3];
                const int   i0 = ip[0], i1 = ip[1], i2 = ip[2], i3 = ip[3];
                #pragma unroll
                for (int i = 0; i < 4; ++i) {
                    const int cp = c0 + i*8;
                    const float* xp = x + ((size_t)n*C_ + cbase + cp)*HW_;
                    const float s = w0c*xp[i0] + w1c*xp[i1] + w2c*xp[i2] + w3c*xp[i3];
                    sl[cp*32 + p] = s;
                }
            }
            __syncthreads();
            #pragma unroll 8
            for (int cp = 0; cp < 32; ++cp) {
                const float4 wv = *(const float4*)&wl[cp*128 + og*4];
                const float4 sv = *(const float4*)&sl[cp*32  + pg*4];
                const float wa[4] = {wv.x, wv.y, wv.z, wv.w};
                const float sa[4] = {sv.x, sv.y, sv.z, sv.w};
                #pragma unroll
                for (int i = 0; i < 4; ++i)
                    #pragma unroll
                    for (int j = 0; j < 4; ++j)
                        acc[i][j] += wa[i]*sa[j];
            }
            __syncthreads();
        }
    }

    // ---- epilogue: bias, store pre-BN, per-channel partial sums ----
    float bsum[4], bsq[4];
    #pragma unroll
    for (int i = 0; i < 4; ++i) {
        const int o = og*4 + i;
        const float b = bias[o];
        float4 v4;
        float vv[4];
        #pragma unroll
        for (int j = 0; j < 4; ++j) vv[j] = acc[i][j] + b;
        v4.x = vv[0]; v4.y = vv[1]; v4.z = vv[2]; v4.w = vv[3];
        *(float4*)&out_pre[(((size_t)n*CO_ + o)*H_ + h)*W_ + w0 + pg*4] = v4;
        bsum[i] = vv[0]+vv[1]+vv[2]+vv[3];
        bsq[i]  = vv[0]*vv[0]+vv[1]*vv[1]+vv[2]*vv[2]+vv[3]*vv[3];
    }
    // reduce across the 8 pg lanes (contiguous within wave: t = og*8+pg)
    #pragma unroll
    for (int i = 0; i < 4; ++i) {
        #pragma unroll
        for (int d = 4; d >= 1; d >>= 1) {
            bsum[i] += __shfl_down(bsum[i], d, 8);
            bsq[i]  += __shfl_down(bsq[i],  d, 8);
        }
    }
    if (pg == 0) {
        #pragma unroll
        for (int i = 0; i < 4; ++i) {
            const int o = og*4 + i;
            atomicAdd(&bnsum[o], bsum[i]);
            atomicAdd(&bnsq[o],  bsq[i]);
        }
    }
}

// K3: BN finalize + ReLU (float4).
__global__ __launch_bounds__(256)
void k_bn(const float* __restrict__ out_pre,
          const float* __restrict__ bnsum, const float* __restrict__ bnsq,
          const float* __restrict__ gamma, const float* __restrict__ beta,
          float* __restrict__ out) {
    const int e4 = blockIdx.x*256 + threadIdx.x;
    const int total4 = N_*CO_*HW_/4;
    if (e4 >= total4) return;
    const int o = ((e4*4) / HW_) % CO_;
    const float invM = 1.0f / (float)(N_*HW_);
    const float mean = bnsum[o] * invM;
    const float var  = bnsq[o] * invM - mean*mean;
    const float inv  = rsqrtf(var + BN_EPS_);
    const float g    = gamma[o] * inv;
    const float sh   = beta[o] - mean * g;
    float4 v = ((const float4*)out_pre)[e4];
    v.x = fmaxf(v.x*g + sh, 0.0f);
    v.y = fmaxf(v.y*g + sh, 0.0f);
    v.z = fmaxf(v.z*g + sh, 0.0f);
    v.w = fmaxf(v.w*g + sh, 0.0f);
    ((float4*)out)[e4] = v;
}

extern "C" void kernel_launch(void* const* d_in, const int* in_sizes, int n_in,
                              void* d_out, int out_size, void* d_ws, size_t ws_size,
                              hipStream_t stream) {
    const float* x      = (const float*)d_in[0];
    const float* offw   = (const float*)d_in[1];
    const float* offb   = (const float*)d_in[2];
    const float* modw   = (const float*)d_in[3];
    const float* modb   = (const float*)d_in[4];
    const float* weight = (const float*)d_in[5];
    const float* bias   = (const float*)d_in[6];
    const float* gamma  = (const float*)d_in[7];
    const float* beta   = (const float*)d_in[8];
    float* out = (float*)d_out;

    float* wsf     = (float*)d_ws;
    float* convout = wsf;
    float* wT      = wsf + 995328;
    float* out_pre = wsf + 995328 + 147456;
    float* bn      = wsf + 995328 + 147456 + 4718592;

    hipMemsetAsync(bn, 0, 256*sizeof(float), stream);
    k_offconv<<<dim3(36, NJ, N_), 256, 0, stream>>>(x, offw, offb, modw, modb, convout);
    k_wtrans<<<(9*C_*CO_ + 255)/256, 256, 0, stream>>>(weight, wT);
    k_main<<<N_*H_*3, 256, 0, stream>>>(x, convout, wT, bias, out_pre, bn, bn + 128);
    k_bn<<<(N_*CO_*HW_/4 + 255)/256, 256, 0, stream>>>(out_pre, bn, bn + 128, gamma, beta, out);
}

// Round 2
// 357.766 us; speedup vs baseline: 2.2474x; 2.2474x over previous
//
#include <hip/hip_runtime.h>
#include <math.h>

#define N_   4
#define C_   128
#define CO_  128
#define H_   96
#define W_   96
#define HW_  (H_*W_)
#define BN_EPS_ 1e-5f

typedef short bf16x8 __attribute__((ext_vector_type(8)));
typedef float f32x4  __attribute__((ext_vector_type(4)));
typedef unsigned short ushortx8 __attribute__((ext_vector_type(8)));

__device__ __forceinline__ unsigned short f2bf(float f) {
    unsigned u = __builtin_bit_cast(unsigned, f);
    unsigned r = (u + 0x7fffu + ((u >> 16) & 1u)) >> 16;
    return (unsigned short)r;
}

// ---------------------------------------------------------------------------
// ws layout (floats):
//   convout : 4*27*9216          = 995328
//   out_pre : 4*128*9216         = 4718592   (at 995328)
//   bn      : 256                           (at 5713920)
//   wjT     : 36864 ushorts  (18432 floats) (at 5714176)  [kk][k_hi][j32][k_lo8]
//   wTA     : 147456 ushorts (73728 floats) (at 5732608)  [kk][k_hi][o128][k_lo8]
// total ~23.2 MB
// ---------------------------------------------------------------------------
#define WS_CONVOUT 0
#define WS_OUTPRE  995328
#define WS_BN      5713920
#define WS_WJT     5714176
#define WS_WTA     5732608

// K index ordering for both GEMMs: K = ktap*128 + c ; chunk kk (36 chunks of 32):
// ktap = kk>>2, c = (kk&3)*32 + k_hi*8 + k_lo.

__global__ __launch_bounds__(256)
void k_prep(const float* __restrict__ offw, const float* __restrict__ modw,
            const float* __restrict__ weight,
            unsigned short* __restrict__ wjT, unsigned short* __restrict__ wTA) {
    const int e = blockIdx.x*256 + threadIdx.x;   // 720*256 = 184320 exact
    if (e < 36864) {
        const int k_lo = e & 7, j = (e >> 3) & 31, k_hi = (e >> 8) & 3, kk = e >> 10;
        const int c  = (kk & 3)*32 + k_hi*8 + k_lo;
        const int kt = kk >> 2;
        float v = 0.0f;
        if (j < 18)      v = offw[(j*C_ + c)*9 + kt];
        else if (j < 27) v = modw[((j-18)*C_ + c)*9 + kt];
        wjT[e] = f2bf(v);
    } else {
        const int e2 = e - 36864;
        const int k_lo = e2 & 7, o = (e2 >> 3) & 127, k_hi = (e2 >> 10) & 3, kk = e2 >> 12;
        const int c  = (kk & 3)*32 + k_hi*8 + k_lo;
        const int kt = kk >> 2;
        wTA[e2] = f2bf(weight[(o*C_ + c)*9 + kt]);
    }
}

// Offset/mod conv as bf16 MFMA GEMM. Block: 64 pixels x 32 j (27 used).
// grid (144, 4). 256 threads = 4 waves; wave w handles p-subtile w*16.
__global__ __launch_bounds__(256)
void k_offconv(const float* __restrict__ x,
               const unsigned short* __restrict__ wjT,
               const float* __restrict__ offb, const float* __restrict__ modb,
               float* __restrict__ convout) {
    __shared__ unsigned short Alds[4*32*8];   // [k_hi][j][k_lo]  2 KB
    __shared__ unsigned short Blds[4*64*8];   // [k_hi][p][k_lo]  4 KB

    const int t    = threadIdx.x;
    const int n    = blockIdx.y;
    const int p0   = blockIdx.x*64;
    const int wid  = t >> 6;
    const int lane = t & 63;
    const int quad = lane >> 4;
    const int l16  = lane & 15;

    f32x4 acc0 = {0.f,0.f,0.f,0.f};
    f32x4 acc1 = {0.f,0.f,0.f,0.f};

    const int ps = t & 63;          // staging pixel
    const int khs = t >> 6;         // staging k_hi
    const int pix_s = p0 + ps;
    const int hs = pix_s / W_;
    const int ws = pix_s - hs*W_;

    for (int kk = 0; kk < 36; ++kk) {
        const int kt = kk >> 2;
        const int cbase = (kk & 3)*32 + khs*8;
        const int dy = kt/3 - 1, dx = kt%3 - 1;
        // stage A (2 KB contiguous)
        ((uint2*)Alds)[t] = ((const uint2*)(wjT + kk*1024))[t];
        // stage B: shifted coalesced x load with zero pad
        const int y = hs + dy, xw = ws + dx;
        const bool valid = ((unsigned)y < H_) & ((unsigned)xw < W_);
        const int off = y*W_ + xw;
        ushortx8 v;
        const float* xb = x + ((size_t)n*C_ + cbase)*HW_;
        #pragma unroll
        for (int i = 0; i < 8; ++i)
            v[i] = valid ? f2bf(xb[i*HW_ + off]) : (unsigned short)0;
        *(ushortx8*)&Blds[(khs*64 + ps)*8] = v;
        __syncthreads();

        const bf16x8 a0 = *(const bf16x8*)&Alds[(quad*32 + l16)*8];
        const bf16x8 a1 = *(const bf16x8*)&Alds[(quad*32 + 16 + l16)*8];
        const bf16x8 b  = *(const bf16x8*)&Blds[(quad*64 + wid*16 + l16)*8];
        acc0 = __builtin_amdgcn_mfma_f32_16x16x32_bf16(a0, b, acc0, 0, 0, 0);
        acc1 = __builtin_amdgcn_mfma_f32_16x16x32_bf16(a1, b, acc1, 0, 0, 0);
        __syncthreads();
    }

    const int p = p0 + wid*16 + l16;
    #pragma unroll
    for (int r = 0; r < 4; ++r) {
        const int j0 = quad*4 + r;           // mt=0
        convout[((size_t)n*27 + j0)*HW_ + p] = acc0[r] + (j0 < 18 ? offb[j0] : modb[j0-18]);
        const int j1 = 16 + quad*4 + r;      // mt=1
        if (j1 < 27)
            convout[((size_t)n*27 + j1)*HW_ + p] = acc1[r] + modb[j1-18];
    }
}

// Main GEMM: 128 o x 64 p per block, K=1152, bilinear gather fused into staging.
// grid (144, 4). 4 waves; wave w owns o in [w*32, w*32+32).
__global__ __launch_bounds__(256)
void k_gemm(const float* __restrict__ x,
            const float* __restrict__ convout,
            const unsigned short* __restrict__ wTA,
            const float* __restrict__ bias,
            float* __restrict__ out_pre,
            float* __restrict__ bnsum, float* __restrict__ bnsq) {
    __shared__ unsigned short Alds[4*128*8];  // [k_hi][o][k_lo]  8 KB
    __shared__ unsigned short Blds[4*64*8];   // [k_hi][p][k_lo]  4 KB
    __shared__ int4   midx[9][64];            // 9 KB
    __shared__ float4 mwgt[9][64];            // 9 KB

    const int t    = threadIdx.x;
    const int n    = blockIdx.y;
    const int p0   = blockIdx.x*64;
    const int wid  = t >> 6;
    const int lane = t & 63;
    const int quad = lane >> 4;
    const int l16  = lane & 15;

    // ---- Phase A: bilinear metadata for 9 taps x 64 pixels ----
    const float* co = convout + (size_t)n*27*HW_;
    for (int it = t; it < 9*64; it += 256) {
        const int kt = it >> 6, p = it & 63;
        const int pix = p0 + p;
        const int h = pix / W_, w = pix - h*W_;
        const float offy = co[(2*kt  )*HW_ + pix];
        const float offx = co[(2*kt+1)*HW_ + pix];
        const float mraw = co[(18+kt )*HW_ + pix];
        const float m = 2.0f / (1.0f + expf(-mraw));
        const float sy = offy + (float)(h + kt/3 - 1);
        const float sx = offx + (float)(w + kt%3 - 1);
        const float y0f = floorf(sy), x0f = floorf(sx);
        const float wy1 = sy - y0f, wy0 = 1.0f - wy1;
        const float wx1 = sx - x0f, wx0 = 1.0f - wx1;
        int4 idx; float4 wg;
        {
            const float yf[2] = {y0f, y0f + 1.0f};
            const float xf[2] = {x0f, x0f + 1.0f};
            const float wy[2] = {wy0, wy1};
            const float wx[2] = {wx0, wx1};
            int   ii[4]; float ww[4];
            #pragma unroll
            for (int cy = 0; cy < 2; ++cy)
                #pragma unroll
                for (int cx = 0; cx < 2; ++cx) {
                    const bool valid = (yf[cy] >= 0.0f) & (yf[cy] <= (float)(H_-1)) &
                                       (xf[cx] >= 0.0f) & (xf[cx] <= (float)(W_-1));
                    const int yi = (int)fminf(fmaxf(yf[cy], 0.0f), (float)(H_-1));
                    const int xi = (int)fminf(fmaxf(xf[cx], 0.0f), (float)(W_-1));
                    ii[cy*2+cx] = yi*W_ + xi;
                    ww[cy*2+cx] = valid ? (wy[cy]*wx[cx]*m) : 0.0f;
                }
            idx = make_int4(ii[0], ii[1], ii[2], ii[3]);
            wg  = make_float4(ww[0], ww[1], ww[2], ww[3]);
        }
        midx[kt][p] = idx;
        mwgt[kt][p] = wg;
    }
    __syncthreads();

    f32x4 acc[2][4];
    #pragma unroll
    for (int i = 0; i < 2; ++i)
        #pragma unroll
        for (int j = 0; j < 4; ++j) acc[i][j] = (f32x4){0.f,0.f,0.f,0.f};

    const int ps  = t & 63;
    const int khs = t >> 6;

    for (int kk = 0; kk < 36; ++kk) {
        const int kt = kk >> 2;
        const int cbase = (kk & 3)*32 + khs*8;
        // stage A (8 KB contiguous)
        ((uint4*)Alds)[t]       = ((const uint4*)(wTA + kk*4096))[t];
        ((uint4*)Alds)[t + 256] = ((const uint4*)(wTA + kk*4096))[t + 256];
        // stage B: bilinear gather -> bf16, k-split layout
        {
            const int4   idx = midx[kt][ps];
            const float4 wg  = mwgt[kt][ps];
            const float* xb = x + ((size_t)n*C_ + cbase)*HW_;
            ushortx8 v;
            #pragma unroll
            for (int i = 0; i < 8; ++i) {
                const float* xp = xb + i*HW_;
                v[i] = f2bf(wg.x*xp[idx.x] + wg.y*xp[idx.y] + wg.z*xp[idx.z] + wg.w*xp[idx.w]);
            }
            *(ushortx8*)&Blds[(khs*64 + ps)*8] = v;
        }
        __syncthreads();

        const bf16x8 a0 = *(const bf16x8*)&Alds[(quad*128 + wid*32 + l16)*8];
        const bf16x8 a1 = *(const bf16x8*)&Alds[(quad*128 + wid*32 + 16 + l16)*8];
        #pragma unroll
        for (int nt = 0; nt < 4; ++nt) {
            const bf16x8 b = *(const bf16x8*)&Blds[(quad*64 + nt*16 + l16)*8];
            acc[0][nt] = __builtin_amdgcn_mfma_f32_16x16x32_bf16(a0, b, acc[0][nt], 0, 0, 0);
            acc[1][nt] = __builtin_amdgcn_mfma_f32_16x16x32_bf16(a1, b, acc[1][nt], 0, 0, 0);
        }
        __syncthreads();
    }

    // ---- epilogue: bias, store pre-BN, BN partial sums ----
    #pragma unroll
    for (int mt = 0; mt < 2; ++mt) {
        #pragma unroll
        for (int r = 0; r < 4; ++r) {
            const int o = wid*32 + mt*16 + quad*4 + r;
            const float b = bias[o];
            float s = 0.f, sq = 0.f;
            #pragma unroll
            for (int nt = 0; nt < 4; ++nt) {
                const int p = p0 + nt*16 + l16;
                const float val = acc[mt][nt][r] + b;
                out_pre[((size_t)n*CO_ + o)*HW_ + p] = val;
                s += val; sq += val*val;
            }
            #pragma unroll
            for (int d = 1; d < 16; d <<= 1) {
                s  += __shfl_xor(s,  d);
                sq += __shfl_xor(sq, d);
            }
            if (l16 == 0) {
                atomicAdd(&bnsum[o], s);
                atomicAdd(&bnsq[o],  sq);
            }
        }
    }
}

// BN finalize + ReLU (float4).
__global__ __launch_bounds__(256)
void k_bn(const float* __restrict__ out_pre,
          const float* __restrict__ bnsum, const float* __restrict__ bnsq,
          const float* __restrict__ gamma, const float* __restrict__ beta,
          float* __restrict__ out) {
    const int e4 = blockIdx.x*256 + threadIdx.x;
    const int total4 = N_*CO_*HW_/4;
    if (e4 >= total4) return;
    const int o = ((e4*4) / HW_) % CO_;
    const float invM = 1.0f / (float)(N_*HW_);
    const float mean = bnsum[o] * invM;
    const float var  = bnsq[o] * invM - mean*mean;
    const float inv  = rsqrtf(var + BN_EPS_);
    const float g    = gamma[o] * inv;
    const float sh   = beta[o] - mean * g;
    float4 v = ((const float4*)out_pre)[e4];
    v.x = fmaxf(v.x*g + sh, 0.0f);
    v.y = fmaxf(v.y*g + sh, 0.0f);
    v.z = fmaxf(v.z*g + sh, 0.0f);
    v.w = fmaxf(v.w*g + sh, 0.0f);
    ((float4*)out)[e4] = v;
}

extern "C" void kernel_launch(void* const* d_in, const int* in_sizes, int n_in,
                              void* d_out, int out_size, void* d_ws, size_t ws_size,
                              hipStream_t stream) {
    const float* x      = (const float*)d_in[0];
    const float* offw   = (const float*)d_in[1];
    const float* offb   = (const float*)d_in[2];
    const float* modw   = (const float*)d_in[3];
    const float* modb   = (const float*)d_in[4];
    const float* weight = (const float*)d_in[5];
    const float* bias   = (const float*)d_in[6];
    const float* gamma  = (const float*)d_in[7];
    const float* beta   = (const float*)d_in[8];
    float* out = (float*)d_out;

    float* wsf = (float*)d_ws;
    float* convout = wsf + WS_CONVOUT;
    float* out_pre = wsf + WS_OUTPRE;
    float* bn      = wsf + WS_BN;
    unsigned short* wjT = (unsigned short*)(wsf + WS_WJT);
    unsigned short* wTA = (unsigned short*)(wsf + WS_WTA);

    hipMemsetAsync(bn, 0, 256*sizeof(float), stream);
    k_prep<<<720, 256, 0, stream>>>(offw, modw, weight, wjT, wTA);
    k_offconv<<<dim3(144, N_), 256, 0, stream>>>(x, wjT, offb, modb, convout);
    k_gemm<<<dim3(144, N_), 256, 0, stream>>>(x, convout, wTA, bias, out_pre, bn, bn + 128);
    k_bn<<<(N_*CO_*HW_/4 + 255)/256, 256, 0, stream>>>(out_pre, bn, bn + 128, gamma, beta, out);
}